// Round 13
// baseline (110.921 us; speedup 1.0000x reference)
//
#include <hip/hip_runtime.h>
#include <math.h>
#include <limits.h>

#define BB 4
#define S 8192
#define C 256
#define NW 2048
#define WS 256
#define PSZ 256
#define DD 32
#define KK 65
#define TOTW (BB * NW) /* 8192 */

#define KC 64
#define LDA 68
#define NBKT 512                /* 16-row buckets per batch */
#define TBKT (BB * NBKT)        /* 2048 */

#define SPAN 128                /* staged rows per attn block */
#define RSTR 260                /* LDS row stride in floats (16B-aligned, skewed) */
#define CHUNK 16                /* sorted windows per attn block */

// ---------------------------------------------------------------------------
// Kernel 0: pack B [256 k][512 cols] = [ Wp^T | Wa ]; zero the 2048 counters.
// ---------------------------------------------------------------------------
__global__ __launch_bounds__(256) void prep_B(const float* __restrict__ Wp,
                                              const float* __restrict__ Wa,
                                              float* __restrict__ Bp,
                                              int* __restrict__ cnt) {
    const int k = blockIdx.x;
    const int t = threadIdx.x;
    Bp[k * 512 + t] = Wp[t * WS + k];
    Bp[k * 512 + 256 + t] = Wa[k * C + t];
    if (k < 8) cnt[k * 256 + t] = 0;
}

// ---------------------------------------------------------------------------
// Kernel 1: f32 blocked GEMM  C[8192 x 512] = ct[8192 x 256] @ B[256 x 512].
// bn 4..7 -> g. bn 0..3 (h cols): fused p_t partial reduction (no h buffer).
// ---------------------------------------------------------------------------
__global__ __launch_bounds__(256, 4) void precomp_gemm(const float* __restrict__ ct,
                                                       const float* __restrict__ Bp,
                                                       const float* __restrict__ Vp,
                                                       float* __restrict__ ptpart,
                                                       float* __restrict__ g) {
    __shared__ __align__(16) float Al[KC][LDA];
    __shared__ __align__(16) float Bl[KC][LDA];

    const int t = threadIdx.x;
    const int bm = blockIdx.x >> 3;
    const int bn = blockIdx.x & 7;
    const int tm = t >> 4;
    const int tn = t & 15;
    const int sm = t >> 2;
    const int sf = t & 3;

    const float4* ct4 = (const float4*)ct;
    const float4* B4  = (const float4*)Bp;

    float acc[4][4] = {{0.f}};

    for (int kc = 0; kc < 256; kc += KC) {
        __syncthreads();
#pragma unroll
        for (int i = 0; i < 4; i++) {
            const float4 a = ct4[(size_t)(bm * 64 + sm) * 64 + (kc >> 2) + sf + i * 4];
            const int kl = (sf + i * 4) * 4;
            Al[kl + 0][sm] = a.x;
            Al[kl + 1][sm] = a.y;
            Al[kl + 2][sm] = a.z;
            Al[kl + 3][sm] = a.w;
        }
#pragma unroll
        for (int i = 0; i < 4; i++) {
            const float4 b = B4[(size_t)(kc + sm) * 128 + bn * 16 + sf + i * 4];
            *(float4*)&Bl[sm][(sf + i * 4) * 4] = b;
        }
        __syncthreads();

#pragma unroll 8
        for (int kk = 0; kk < KC; kk++) {
            const float4 a = *(const float4*)&Al[kk][tm * 4];
            const float4 b = *(const float4*)&Bl[kk][tn * 4];
            acc[0][0] = fmaf(a.x, b.x, acc[0][0]);
            acc[0][1] = fmaf(a.x, b.y, acc[0][1]);
            acc[0][2] = fmaf(a.x, b.z, acc[0][2]);
            acc[0][3] = fmaf(a.x, b.w, acc[0][3]);
            acc[1][0] = fmaf(a.y, b.x, acc[1][0]);
            acc[1][1] = fmaf(a.y, b.y, acc[1][1]);
            acc[1][2] = fmaf(a.y, b.z, acc[1][2]);
            acc[1][3] = fmaf(a.y, b.w, acc[1][3]);
            acc[2][0] = fmaf(a.z, b.x, acc[2][0]);
            acc[2][1] = fmaf(a.z, b.y, acc[2][1]);
            acc[2][2] = fmaf(a.z, b.z, acc[2][2]);
            acc[2][3] = fmaf(a.z, b.w, acc[2][3]);
            acc[3][0] = fmaf(a.w, b.x, acc[3][0]);
            acc[3][1] = fmaf(a.w, b.y, acc[3][1]);
            acc[3][2] = fmaf(a.w, b.z, acc[3][2]);
            acc[3][3] = fmaf(a.w, b.w, acc[3][3]);
        }
    }

    if (bn >= 4) {
        const int col = bn * 64 + tn * 4 - 256;
#pragma unroll
        for (int i = 0; i < 4; i++) {
            const int row = bm * 64 + tm * 4 + i;
            *(float4*)&g[(size_t)row * 256 + col] =
                make_float4(acc[i][0], acc[i][1], acc[i][2], acc[i][3]);
        }
    } else {
        const float4 vp4 = ((const float4*)Vp)[bn * 16 + tn];
#pragma unroll
        for (int i = 0; i < 4; i++) {
            float v = tanhf(acc[i][0]) * vp4.x;
            v = fmaf(tanhf(acc[i][1]), vp4.y, v);
            v = fmaf(tanhf(acc[i][2]), vp4.z, v);
            v = fmaf(tanhf(acc[i][3]), vp4.w, v);
#pragma unroll
            for (int off = 8; off >= 1; off >>= 1) v += __shfl_xor(v, off);
            if (tn == 0) {
                const int row = bm * 64 + tm * 4 + i;
                ptpart[row * 4 + bn] = v;
            }
        }
    }
}

// ---------------------------------------------------------------------------
// Kernel 2: finalize p_t + 16-row-bucket histogram (parallel, 32 blocks).
// ---------------------------------------------------------------------------
__global__ __launch_bounds__(256) void pt_hist(const float* __restrict__ ptpart,
                                               float* __restrict__ pt,
                                               int* __restrict__ cnt) {
    const int wg = blockIdx.x * 256 + threadIdx.x;
    const float4 pp = ((const float4*)ptpart)[wg];
    const float x = (pp.x + pp.y) + (pp.z + pp.w);
    const float p = (float)S / (1.f + expf(-x));
    pt[wg] = p;
    const int s0 = (int)p;
    const int bkt = (wg >> 11) * NBKT + min(NBKT - 1, max(0, s0 >> 4));
    atomicAdd(&cnt[bkt], 1);
}

// ---------------------------------------------------------------------------
// Kernel 3: exclusive scan of 2048 bucket counts (1 block, 8 buckets/thread).
// ---------------------------------------------------------------------------
__global__ __launch_bounds__(256) void scan_kernel(const int* __restrict__ cnt,
                                                   int* __restrict__ offs) {
    __shared__ int sh[256];
    const int t = threadIdx.x;
    int v[8];
    int sum = 0;
#pragma unroll
    for (int i = 0; i < 8; i++) { v[i] = cnt[t * 8 + i]; sum += v[i]; }
    sh[t] = sum;
    __syncthreads();
    for (int d = 1; d < 256; d <<= 1) {
        const int x = (t >= d) ? sh[t - d] : 0;
        __syncthreads();
        sh[t] += x;
        __syncthreads();
    }
    int run = (t > 0) ? sh[t - 1] : 0;
#pragma unroll
    for (int i = 0; i < 8; i++) { offs[t * 8 + i] = run; run += v[i]; }
}

// ---------------------------------------------------------------------------
// Kernel 4: scatter window ids into position-sorted permutation (32 blocks).
// ---------------------------------------------------------------------------
__global__ __launch_bounds__(256) void scatter_kernel(const float* __restrict__ pt,
                                                      int* __restrict__ offs,
                                                      int* __restrict__ perm) {
    const int wg = blockIdx.x * 256 + threadIdx.x;
    const int s0 = (int)pt[wg];
    const int bkt = (wg >> 11) * NBKT + min(NBKT - 1, max(0, s0 >> 4));
    const int pos = atomicAdd(&offs[bkt], 1);
    perm[pos] = wg;
}

// ---------------------------------------------------------------------------
// Kernel 5: gather-attention v9 — LDS-STAGED TILES. R12 lesson: three attn
// structures all hit ~44us = L2 scattered-gather bound (533MB @ ~12TB/s);
// only cutting traffic wins. Block = 16 consecutive sorted windows (dense:
// ~100-row union span). Stage SPAN=128 rows once into LDS (133KB); all
// score/accum reads hit LDS. Rows outside span / other-batch windows fall
// back to global (rare, correct). 1024 thr = 4 window-groups x 4 rounds.
// ---------------------------------------------------------------------------
__global__ __launch_bounds__(1024) void attn(const float* __restrict__ q,
                                             const float* __restrict__ g,
                                             const float* __restrict__ pt,
                                             const int* __restrict__ perm,
                                             float* __restrict__ out) {
    __shared__ __align__(16) float qlds[SPAN * RSTR];     // 133,120 B
    __shared__ __align__(16) float4 accbuf[4][4][64];     // 16 KB
    __shared__ float mbuf[4][4], dbuf[4][4];
    __shared__ int wgs[CHUNK];
    __shared__ float pts[CHUNK];
    __shared__ int baseSh;

    const int tid = threadIdx.x;          // 0..1023
    const int bid = blockIdx.x;           // 0..511
    const int chunk = (bid & 7) * 64 + (bid >> 3);   // XCD-chunked

    if (tid < CHUNK) {
        const int w = perm[chunk * CHUNK + tid];
        wgs[tid] = w;
        pts[tid] = pt[w];
    }
    __syncthreads();

    if (tid == 0) {
        const int b0 = wgs[0] >> 11;
        int mn = INT_MAX;
#pragma unroll
        for (int i = 0; i < CHUNK; i++)
            if ((wgs[i] >> 11) == b0) mn = min(mn, (int)pts[i]);
        int base = mn - DD;
        baseSh = max(0, min(base, S - SPAN));
    }
    __syncthreads();

    const int base = baseSh;
    const int batch0 = wgs[0] >> 11;

    // ---- stage SPAN rows of batch0's q into LDS (coalesced, skewed rows) ----
    {
        const float4* src = (const float4*)(q + ((size_t)batch0 * S + base) * C);
#pragma unroll
        for (int i = 0; i < 8; i++) {
            const int f = tid + i * 1024;          // 0..8191
            const int r = f >> 6, c = f & 63;
            *(float4*)&qlds[r * RSTR + c * 4] = src[(size_t)r * 64 + c];
        }
    }
    __syncthreads();

    const int grp = tid >> 8;              // window-group 0..3
    const int t256 = tid & 255;
    const int l = tid & 63;
    const int wv = (tid >> 6) & 3;         // wave within group
    const int gw = (t256 >> 4) & 3;        // kslot within wave
    const int sub = t256 & 15;             // channel sub-slot
    const int kslot = t256 >> 4;           // 0..15

    for (int rnd = 0; rnd < 4; rnd++) {
        const int widx = rnd * 4 + grp;
        const int wg = wgs[widx];
        const float p = pts[widx];
        const int s0 = (int)p;
        const int wb = wg >> 11;
        const bool sameb = (wb == batch0);
        const float* qg = q + (size_t)wb * S * C + sub * 4;

        const float* grow = g + (size_t)wg * C + sub * 4;
        const float4 g0 = *(const float4*)(grow);
        const float4 g1 = *(const float4*)(grow + 64);
        const float4 g2 = *(const float4*)(grow + 128);
        const float4 g3 = *(const float4*)(grow + 192);

        // ---- scores ----
        float e[5];
#pragma unroll
        for (int it = 0; it < 5; it++) {
            const int k = it * 16 + kslot;
            const int s = s0 + k - DD;
            const bool valid = (k <= 64) && ((unsigned)s < (unsigned)S);
            const int rr = min(max(s, 0), S - 1);
            const int idx = rr - base;
            float4 q0, q1, q2, q3;
            if (sameb && (unsigned)idx < (unsigned)SPAN) {
                const float* lp = &qlds[idx * RSTR + sub * 4];
                q0 = *(const float4*)(lp);
                q1 = *(const float4*)(lp + 64);
                q2 = *(const float4*)(lp + 128);
                q3 = *(const float4*)(lp + 192);
            } else {
                const float* gp = qg + (size_t)rr * C;
                q0 = *(const float4*)(gp);
                q1 = *(const float4*)(gp + 64);
                q2 = *(const float4*)(gp + 128);
                q3 = *(const float4*)(gp + 192);
            }
            float d0 = q0.x * g0.x, d1 = q1.x * g1.x;
            float d2 = q2.x * g2.x, d3 = q3.x * g3.x;
            d0 = fmaf(q0.y, g0.y, d0); d1 = fmaf(q1.y, g1.y, d1);
            d2 = fmaf(q2.y, g2.y, d2); d3 = fmaf(q3.y, g3.y, d3);
            d0 = fmaf(q0.z, g0.z, d0); d1 = fmaf(q1.z, g1.z, d1);
            d2 = fmaf(q2.z, g2.z, d2); d3 = fmaf(q3.z, g3.z, d3);
            d0 = fmaf(q0.w, g0.w, d0); d1 = fmaf(q1.w, g1.w, d1);
            d2 = fmaf(q2.w, g2.w, d2); d3 = fmaf(q3.w, g3.w, d3);
            float d = (d0 + d1) + (d2 + d3);
#pragma unroll
            for (int off = 8; off >= 1; off >>= 1) d += __shfl_xor(d, off);
            e[it] = valid ? d : -3e38f;
        }

        // ---- wave-local softmax ----
        float m = e[0];
#pragma unroll
        for (int it = 1; it < 5; it++) m = fmaxf(m, e[it]);
        m = fmaxf(m, __shfl_xor(m, 16));
        m = fmaxf(m, __shfl_xor(m, 32));

        float den = 0.f;
#pragma unroll
        for (int it = 0; it < 5; it++) {
            e[it] = __expf(e[it] - m);
            den += e[it];
        }
        den += __shfl_xor(den, 16);
        den += __shfl_xor(den, 32);

#pragma unroll
        for (int it = 0; it < 5; it++) {
            const float fs = (float)(s0 + it * 16 + kslot - DD) - p;
            const float tt = fs * (1.f / (float)DD);
            e[it] *= __expf(-2.f * tt * tt);
        }

        // ---- weighted accumulation (rows re-read: LDS-hot) ----
        float4 a0 = {0,0,0,0}, a1 = {0,0,0,0}, a2 = {0,0,0,0}, a3 = {0,0,0,0};
#pragma unroll
        for (int it = 0; it < 5; it++) {
            const int s = s0 + it * 16 + kslot - DD;
            const int rr = min(max(s, 0), S - 1);
            const int idx = rr - base;
            float4 q0, q1, q2, q3;
            if (sameb && (unsigned)idx < (unsigned)SPAN) {
                const float* lp = &qlds[idx * RSTR + sub * 4];
                q0 = *(const float4*)(lp);
                q1 = *(const float4*)(lp + 64);
                q2 = *(const float4*)(lp + 128);
                q3 = *(const float4*)(lp + 192);
            } else {
                const float* gp = qg + (size_t)rr * C;
                q0 = *(const float4*)(gp);
                q1 = *(const float4*)(gp + 64);
                q2 = *(const float4*)(gp + 128);
                q3 = *(const float4*)(gp + 192);
            }
            const float w = e[it];
            a0.x = fmaf(w, q0.x, a0.x); a0.y = fmaf(w, q0.y, a0.y);
            a0.z = fmaf(w, q0.z, a0.z); a0.w = fmaf(w, q0.w, a0.w);
            a1.x = fmaf(w, q1.x, a1.x); a1.y = fmaf(w, q1.y, a1.y);
            a1.z = fmaf(w, q1.z, a1.z); a1.w = fmaf(w, q1.w, a1.w);
            a2.x = fmaf(w, q2.x, a2.x); a2.y = fmaf(w, q2.y, a2.y);
            a2.z = fmaf(w, q2.z, a2.z); a2.w = fmaf(w, q2.w, a2.w);
            a3.x = fmaf(w, q3.x, a3.x); a3.y = fmaf(w, q3.y, a3.y);
            a3.z = fmaf(w, q3.z, a3.z); a3.w = fmaf(w, q3.w, a3.w);
        }

        // ---- merge wave's 4 kslots (shared M_w -> plain adds) ----
#define MERGE(v) { v += __shfl_xor(v, 16); v += __shfl_xor(v, 32); }
        MERGE(a0.x) MERGE(a0.y) MERGE(a0.z) MERGE(a0.w)
        MERGE(a1.x) MERGE(a1.y) MERGE(a1.z) MERGE(a1.w)
        MERGE(a2.x) MERGE(a2.y) MERGE(a2.z) MERGE(a2.w)
        MERGE(a3.x) MERGE(a3.y) MERGE(a3.z) MERGE(a3.w)
#undef MERGE

        float4 o = a0;
        if (gw == 1) o = a1;
        else if (gw == 2) o = a2;
        else if (gw == 3) o = a3;
        accbuf[grp][wv][l] = o;
        if (l == 0) { mbuf[grp][wv] = m; dbuf[grp][wv] = den; }
        __syncthreads();

        // ---- cross-wave merge with rescale; first wave of group writes ----
        if (t256 < 64) {
            const float M = fmaxf(fmaxf(mbuf[grp][0], mbuf[grp][1]),
                                  fmaxf(mbuf[grp][2], mbuf[grp][3]));
            const float sc0 = __expf(mbuf[grp][0] - M);
            const float sc1 = __expf(mbuf[grp][1] - M);
            const float sc2 = __expf(mbuf[grp][2] - M);
            const float sc3 = __expf(mbuf[grp][3] - M);
            const float dtot = dbuf[grp][0]*sc0 + dbuf[grp][1]*sc1 +
                               dbuf[grp][2]*sc2 + dbuf[grp][3]*sc3;
            const float4 v0 = accbuf[grp][0][t256];
            const float4 v1 = accbuf[grp][1][t256];
            const float4 v2 = accbuf[grp][2][t256];
            const float4 v3 = accbuf[grp][3][t256];
            const float r = 1.f / dtot;
            float4 oo;
            oo.x = (v0.x*sc0 + v1.x*sc1 + v2.x*sc2 + v3.x*sc3) * r;
            oo.y = (v0.y*sc0 + v1.y*sc1 + v2.y*sc2 + v3.y*sc3) * r;
            oo.z = (v0.z*sc0 + v1.z*sc1 + v2.z*sc2 + v3.z*sc3) * r;
            oo.w = (v0.w*sc0 + v1.w*sc1 + v2.w*sc2 + v3.w*sc3) * r;
            *(float4*)(out + (size_t)wg * C + t256 * 4) = oo;
        }
        __syncthreads();
    }
}

// ---------------------------------------------------------------------------
extern "C" void kernel_launch(void* const* d_in, const int* in_sizes, int n_in,
                              void* d_out, int out_size, void* d_ws, size_t ws_size,
                              hipStream_t stream) {
    const float* q  = (const float*)d_in[0];
    const float* ct = (const float*)d_in[1];
    const float* Wa = (const float*)d_in[2];
    const float* Wp = (const float*)d_in[3];
    const float* Vp = (const float*)d_in[4];
    float* out = (float*)d_out;

    char* ws = (char*)d_ws;
    float* Bp     = (float*)ws;                   // 512 KB
    float* ptpart = (float*)(ws + 524288);        // 128 KB
    float* pt     = (float*)(ws + 655360);        // 32 KB
    int*   cnt    = (int*)  (ws + 688128);        // 8 KB
    int*   offs   = (int*)  (ws + 696320);        // 8 KB
    int*   perm   = (int*)  (ws + 704512);        // 32 KB
    float* g      = (float*)(ws + 737280);        // 8 MB

    prep_B<<<256, 256, 0, stream>>>(Wp, Wa, Bp, cnt);
    precomp_gemm<<<1024, 256, 0, stream>>>(ct, Bp, Vp, ptpart, g);
    pt_hist<<<TOTW / 256, 256, 0, stream>>>(ptpart, pt, cnt);
    scan_kernel<<<1, 256, 0, stream>>>(cnt, offs);
    scatter_kernel<<<TOTW / 256, 256, 0, stream>>>(pt, offs, perm);
    attn<<<TOTW / CHUNK, 1024, 0, stream>>>(q, g, pt, perm, out);
}

// Round 14
// 96.595 us; speedup vs baseline: 1.1483x; 1.1483x over previous
//
#include <hip/hip_runtime.h>
#include <math.h>

#define BB 4
#define S 8192
#define C 256
#define NW 2048
#define WS 256
#define PSZ 256
#define DD 32
#define KK 65
#define TOTW (BB * NW) /* 8192 */

#define KC 64
#define LDA 68
#define NBKT 64
#define TBKT (BB * NBKT)   /* 256 */

// ---------------------------------------------------------------------------
// Kernel 0: pack B [256 k][512 cols] = [ Wp^T | Wa ]; zero bucket counters.
// ---------------------------------------------------------------------------
__global__ __launch_bounds__(256) void prep_B(const float* __restrict__ Wp,
                                              const float* __restrict__ Wa,
                                              float* __restrict__ Bp,
                                              int* __restrict__ cnt) {
    const int k = blockIdx.x;
    const int t = threadIdx.x;
    Bp[k * 512 + t] = Wp[t * WS + k];
    Bp[k * 512 + 256 + t] = Wa[k * C + t];
    if (k == 0) cnt[t] = 0;
}

// ---------------------------------------------------------------------------
// Kernel 1: f32 blocked GEMM  C[8192 x 512] = ct[8192 x 256] @ B[256 x 512].
// bn 4..7 -> g. bn 0..3 (h cols): fused p_t partial reduction (no h buffer).
// ---------------------------------------------------------------------------
__global__ __launch_bounds__(256, 4) void precomp_gemm(const float* __restrict__ ct,
                                                       const float* __restrict__ Bp,
                                                       const float* __restrict__ Vp,
                                                       float* __restrict__ ptpart,
                                                       float* __restrict__ g) {
    __shared__ __align__(16) float Al[KC][LDA];
    __shared__ __align__(16) float Bl[KC][LDA];

    const int t = threadIdx.x;
    const int bm = blockIdx.x >> 3;
    const int bn = blockIdx.x & 7;
    const int tm = t >> 4;
    const int tn = t & 15;
    const int sm = t >> 2;
    const int sf = t & 3;

    const float4* ct4 = (const float4*)ct;
    const float4* B4  = (const float4*)Bp;

    float acc[4][4] = {{0.f}};

    for (int kc = 0; kc < 256; kc += KC) {
        __syncthreads();
#pragma unroll
        for (int i = 0; i < 4; i++) {
            const float4 a = ct4[(size_t)(bm * 64 + sm) * 64 + (kc >> 2) + sf + i * 4];
            const int kl = (sf + i * 4) * 4;
            Al[kl + 0][sm] = a.x;
            Al[kl + 1][sm] = a.y;
            Al[kl + 2][sm] = a.z;
            Al[kl + 3][sm] = a.w;
        }
#pragma unroll
        for (int i = 0; i < 4; i++) {
            const float4 b = B4[(size_t)(kc + sm) * 128 + bn * 16 + sf + i * 4];
            *(float4*)&Bl[sm][(sf + i * 4) * 4] = b;
        }
        __syncthreads();

#pragma unroll 8
        for (int kk = 0; kk < KC; kk++) {
            const float4 a = *(const float4*)&Al[kk][tm * 4];
            const float4 b = *(const float4*)&Bl[kk][tn * 4];
            acc[0][0] = fmaf(a.x, b.x, acc[0][0]);
            acc[0][1] = fmaf(a.x, b.y, acc[0][1]);
            acc[0][2] = fmaf(a.x, b.z, acc[0][2]);
            acc[0][3] = fmaf(a.x, b.w, acc[0][3]);
            acc[1][0] = fmaf(a.y, b.x, acc[1][0]);
            acc[1][1] = fmaf(a.y, b.y, acc[1][1]);
            acc[1][2] = fmaf(a.y, b.z, acc[1][2]);
            acc[1][3] = fmaf(a.y, b.w, acc[1][3]);
            acc[2][0] = fmaf(a.z, b.x, acc[2][0]);
            acc[2][1] = fmaf(a.z, b.y, acc[2][1]);
            acc[2][2] = fmaf(a.z, b.z, acc[2][2]);
            acc[2][3] = fmaf(a.z, b.w, acc[2][3]);
            acc[3][0] = fmaf(a.w, b.x, acc[3][0]);
            acc[3][1] = fmaf(a.w, b.y, acc[3][1]);
            acc[3][2] = fmaf(a.w, b.z, acc[3][2]);
            acc[3][3] = fmaf(a.w, b.w, acc[3][3]);
        }
    }

    if (bn >= 4) {
        const int col = bn * 64 + tn * 4 - 256;
#pragma unroll
        for (int i = 0; i < 4; i++) {
            const int row = bm * 64 + tm * 4 + i;
            *(float4*)&g[(size_t)row * 256 + col] =
                make_float4(acc[i][0], acc[i][1], acc[i][2], acc[i][3]);
        }
    } else {
        const float4 vp4 = ((const float4*)Vp)[bn * 16 + tn];
#pragma unroll
        for (int i = 0; i < 4; i++) {
            float v = tanhf(acc[i][0]) * vp4.x;
            v = fmaf(tanhf(acc[i][1]), vp4.y, v);
            v = fmaf(tanhf(acc[i][2]), vp4.z, v);
            v = fmaf(tanhf(acc[i][3]), vp4.w, v);
#pragma unroll
            for (int off = 8; off >= 1; off >>= 1) v += __shfl_xor(v, off);
            if (tn == 0) {
                const int row = bm * 64 + tm * 4 + i;
                ptpart[row * 4 + bn] = v;
            }
        }
    }
}

// ---------------------------------------------------------------------------
// Kernel 2: finalize p_t + position histogram (parallel, 32 blocks).
// ---------------------------------------------------------------------------
__global__ __launch_bounds__(256) void pt_hist(const float* __restrict__ ptpart,
                                               float* __restrict__ pt,
                                               int* __restrict__ cnt) {
    const int wg = blockIdx.x * 256 + threadIdx.x;
    const float4 pp = ((const float4*)ptpart)[wg];
    const float x = (pp.x + pp.y) + (pp.z + pp.w);
    const float p = (float)S / (1.f + expf(-x));
    pt[wg] = p;
    const int s0 = (int)p;
    const int bkt = (wg >> 11) * NBKT + min(NBKT - 1, max(0, s0 >> 7));
    atomicAdd(&cnt[bkt], 1);
}

// ---------------------------------------------------------------------------
// Kernel 3: exclusive scan of 256 bucket counts.
// ---------------------------------------------------------------------------
__global__ __launch_bounds__(256) void scan_kernel(const int* __restrict__ cnt,
                                                   int* __restrict__ offs) {
    __shared__ int sh[TBKT];
    const int t = threadIdx.x;
    const int v = cnt[t];
    sh[t] = v;
    __syncthreads();
    for (int d = 1; d < TBKT; d <<= 1) {
        const int x = (t >= d) ? sh[t - d] : 0;
        __syncthreads();
        sh[t] += x;
        __syncthreads();
    }
    offs[t] = sh[t] - v;
}

// ---------------------------------------------------------------------------
// Kernel 4: scatter window ids into position-sorted permutation (32 blocks).
// ---------------------------------------------------------------------------
__global__ __launch_bounds__(256) void scatter_kernel(const float* __restrict__ pt,
                                                      int* __restrict__ offs,
                                                      int* __restrict__ perm) {
    const int wg = blockIdx.x * 256 + threadIdx.x;
    const int s0 = (int)pt[wg];
    const int bkt = (wg >> 11) * NBKT + min(NBKT - 1, max(0, s0 >> 7));
    const int pos = atomicAdd(&offs[bkt], 1);
    perm[pos] = wg;
}

// ---------------------------------------------------------------------------
// Kernel 5: gather-attention v10 = R12 v8 + ASM-PINNED q registers.
// R13 lesson: LDS staging = intrinsic 4-way bank conflict (5M cycles), revert.
// R12 lesson: launch_bounds doesn't stop the compiler rematerializing the
// q loads (VGPR stayed 60 -> 2nd L2 pass). v10 makes the reload ILLEGAL:
// asm volatile("" : "+v"(x)) on every loaded component marks it modified,
// so the accum phase MUST consume the held register. Single L2 pass:
// 1.07GB -> 533MB gather. Success signal: VGPR ~130-160, no scratch.
// ---------------------------------------------------------------------------
__global__ __launch_bounds__(256) void attn(const float* __restrict__ q,
                                            const float* __restrict__ g,
                                            const float* __restrict__ pt,
                                            const int* __restrict__ perm,
                                            float* __restrict__ out) {
    __shared__ __align__(16) float4 accbuf[4][64];
    __shared__ float mbuf[4], dbuf[4];

    const int tid = threadIdx.x;
    const int l = tid & 63;
    const int wv = tid >> 6;
    const int gw = l >> 4;                 // kslot within wave
    const int sub = l & 15;                // channel sub-slot
    const int kslot = tid >> 4;            // 0..15

    const int bid = blockIdx.x;
    const int sb = (bid & 7) * 1024 + (bid >> 3);   // XCD-chunked sorted order
    const int wg = perm[sb];
    const int b = wg >> 11;

    const float p = pt[wg];
    const int s0 = (int)p;

    const float* grow = g + (size_t)wg * C + sub * 4;
    const float4 g0 = *(const float4*)(grow);
    const float4 g1 = *(const float4*)(grow + 64);
    const float4 g2 = *(const float4*)(grow + 128);
    const float4 g3 = *(const float4*)(grow + 192);

    const float* qb = q + (size_t)b * S * C + sub * 4;

    // ---- load all 5 q rows ONCE; pin every component in a VGPR ----
    float4 qh[5][4];
#pragma unroll
    for (int it = 0; it < 5; it++) {
        const int s = s0 + it * 16 + kslot - DD;
        const float* qr = qb + (size_t)min(max(s, 0), S - 1) * C;
        qh[it][0] = *(const float4*)(qr);
        qh[it][1] = *(const float4*)(qr + 64);
        qh[it][2] = *(const float4*)(qr + 128);
        qh[it][3] = *(const float4*)(qr + 192);
    }
#pragma unroll
    for (int it = 0; it < 5; it++) {
        asm volatile("" : "+v"(qh[it][0].x), "+v"(qh[it][0].y),
                          "+v"(qh[it][0].z), "+v"(qh[it][0].w),
                          "+v"(qh[it][1].x), "+v"(qh[it][1].y),
                          "+v"(qh[it][1].z), "+v"(qh[it][1].w),
                          "+v"(qh[it][2].x), "+v"(qh[it][2].y),
                          "+v"(qh[it][2].z), "+v"(qh[it][2].w),
                          "+v"(qh[it][3].x), "+v"(qh[it][3].y),
                          "+v"(qh[it][3].z), "+v"(qh[it][3].w));
    }

    // ---- scores ----
    float e[5];
#pragma unroll
    for (int it = 0; it < 5; it++) {
        const int k = it * 16 + kslot;
        const int s = s0 + k - DD;
        const bool valid = (k <= 64) && ((unsigned)s < (unsigned)S);
        float d0 = qh[it][0].x * g0.x, d1 = qh[it][1].x * g1.x;
        float d2 = qh[it][2].x * g2.x, d3 = qh[it][3].x * g3.x;
        d0 = fmaf(qh[it][0].y, g0.y, d0); d1 = fmaf(qh[it][1].y, g1.y, d1);
        d2 = fmaf(qh[it][2].y, g2.y, d2); d3 = fmaf(qh[it][3].y, g3.y, d3);
        d0 = fmaf(qh[it][0].z, g0.z, d0); d1 = fmaf(qh[it][1].z, g1.z, d1);
        d2 = fmaf(qh[it][2].z, g2.z, d2); d3 = fmaf(qh[it][3].z, g3.z, d3);
        d0 = fmaf(qh[it][0].w, g0.w, d0); d1 = fmaf(qh[it][1].w, g1.w, d1);
        d2 = fmaf(qh[it][2].w, g2.w, d2); d3 = fmaf(qh[it][3].w, g3.w, d3);
        float d = (d0 + d1) + (d2 + d3);
#pragma unroll
        for (int off = 8; off >= 1; off >>= 1) d += __shfl_xor(d, off);
        e[it] = valid ? d : -3e38f;
    }

    // ---- wave-local softmax ----
    float m = e[0];
#pragma unroll
    for (int it = 1; it < 5; it++) m = fmaxf(m, e[it]);
    m = fmaxf(m, __shfl_xor(m, 16));
    m = fmaxf(m, __shfl_xor(m, 32));       // M_w uniform across wave

    float den = 0.f;
#pragma unroll
    for (int it = 0; it < 5; it++) {
        e[it] = __expf(e[it] - m);
        den += e[it];
    }
    den += __shfl_xor(den, 16);
    den += __shfl_xor(den, 32);            // den_w (pre-gauss, per reference)

    // fold gaussian into weights
#pragma unroll
    for (int it = 0; it < 5; it++) {
        const float fs = (float)(s0 + it * 16 + kslot - DD) - p;
        const float tt = fs * (1.f / (float)DD);
        e[it] *= __expf(-2.f * tt * tt);
    }

    // ---- weighted accumulation from PINNED registers (no reload) ----
    float4 a0 = {0,0,0,0}, a1 = {0,0,0,0}, a2 = {0,0,0,0}, a3 = {0,0,0,0};
#pragma unroll
    for (int it = 0; it < 5; it++) {
        const float w = e[it];
        a0.x = fmaf(w, qh[it][0].x, a0.x); a0.y = fmaf(w, qh[it][0].y, a0.y);
        a0.z = fmaf(w, qh[it][0].z, a0.z); a0.w = fmaf(w, qh[it][0].w, a0.w);
        a1.x = fmaf(w, qh[it][1].x, a1.x); a1.y = fmaf(w, qh[it][1].y, a1.y);
        a1.z = fmaf(w, qh[it][1].z, a1.z); a1.w = fmaf(w, qh[it][1].w, a1.w);
        a2.x = fmaf(w, qh[it][2].x, a2.x); a2.y = fmaf(w, qh[it][2].y, a2.y);
        a2.z = fmaf(w, qh[it][2].z, a2.z); a2.w = fmaf(w, qh[it][2].w, a2.w);
        a3.x = fmaf(w, qh[it][3].x, a3.x); a3.y = fmaf(w, qh[it][3].y, a3.y);
        a3.z = fmaf(w, qh[it][3].z, a3.z); a3.w = fmaf(w, qh[it][3].w, a3.w);
    }

    // ---- merge the wave's 4 kslots (shared M_w -> plain adds) ----
#define MERGE(v) { v += __shfl_xor(v, 16); v += __shfl_xor(v, 32); }
    MERGE(a0.x) MERGE(a0.y) MERGE(a0.z) MERGE(a0.w)
    MERGE(a1.x) MERGE(a1.y) MERGE(a1.z) MERGE(a1.w)
    MERGE(a2.x) MERGE(a2.y) MERGE(a2.z) MERGE(a2.w)
    MERGE(a3.x) MERGE(a3.y) MERGE(a3.z) MERGE(a3.w)
#undef MERGE

    float4 o = a0;
    if (gw == 1) o = a1;
    else if (gw == 2) o = a2;
    else if (gw == 3) o = a3;
    accbuf[wv][l] = o;                     // lane l = channel-f4 index
    if (l == 0) { mbuf[wv] = m; dbuf[wv] = den; }
    __syncthreads();

    // ---- cross-wave merge with rescale; first 64 threads write ----
    if (tid < 64) {
        const float M = fmaxf(fmaxf(mbuf[0], mbuf[1]), fmaxf(mbuf[2], mbuf[3]));
        const float sc0 = __expf(mbuf[0] - M);
        const float sc1 = __expf(mbuf[1] - M);
        const float sc2 = __expf(mbuf[2] - M);
        const float sc3 = __expf(mbuf[3] - M);
        const float dtot = dbuf[0]*sc0 + dbuf[1]*sc1 + dbuf[2]*sc2 + dbuf[3]*sc3;
        const float4 v0 = accbuf[0][tid];
        const float4 v1 = accbuf[1][tid];
        const float4 v2 = accbuf[2][tid];
        const float4 v3 = accbuf[3][tid];
        const float r = 1.f / dtot;
        float4 oo;
        oo.x = (v0.x*sc0 + v1.x*sc1 + v2.x*sc2 + v3.x*sc3) * r;
        oo.y = (v0.y*sc0 + v1.y*sc1 + v2.y*sc2 + v3.y*sc3) * r;
        oo.z = (v0.z*sc0 + v1.z*sc1 + v2.z*sc2 + v3.z*sc3) * r;
        oo.w = (v0.w*sc0 + v1.w*sc1 + v2.w*sc2 + v3.w*sc3) * r;
        *(float4*)(out + (size_t)wg * C + tid * 4) = oo;
    }
}

// ---------------------------------------------------------------------------
extern "C" void kernel_launch(void* const* d_in, const int* in_sizes, int n_in,
                              void* d_out, int out_size, void* d_ws, size_t ws_size,
                              hipStream_t stream) {
    const float* q  = (const float*)d_in[0];
    const float* ct = (const float*)d_in[1];
    const float* Wa = (const float*)d_in[2];
    const float* Wp = (const float*)d_in[3];
    const float* Vp = (const float*)d_in[4];
    float* out = (float*)d_out;

    char* ws = (char*)d_ws;
    float* Bp     = (float*)ws;                   // 512 KB
    float* ptpart = (float*)(ws + 524288);        // 128 KB
    float* pt     = (float*)(ws + 655360);        // 32 KB
    int*   cnt    = (int*)  (ws + 688128);        // 1 KB
    int*   offs   = (int*)  (ws + 689152);        // 1 KB
    int*   perm   = (int*)  (ws + 690176);        // 32 KB
    float* g      = (float*)(ws + 722944);        // 8 MB

    prep_B<<<256, 256, 0, stream>>>(Wp, Wa, Bp, cnt);
    precomp_gemm<<<1024, 256, 0, stream>>>(ct, Bp, Vp, ptpart, g);
    pt_hist<<<TOTW / 256, 256, 0, stream>>>(ptpart, pt, cnt);
    scan_kernel<<<1, TBKT, 0, stream>>>(cnt, offs);
    scatter_kernel<<<TOTW / 256, 256, 0, stream>>>(pt, offs, perm);
    attn<<<TOTW, 256, 0, stream>>>(q, g, pt, perm, out);
}